// Round 10
// baseline (9144.638 us; speedup 1.0000x reference)
//
#include <hip/hip_runtime.h>
#include <hip/hip_cooperative_groups.h>
#include <cstdint>
#include <cstddef>

namespace cg = cooperative_groups;

// ---------------------------------------------------------------------------
// GAT x3 (exact JAX-threefry dropout, PARTITIONABLE mode) + SAGPool x7.
// Round 14:
//  * Accounting showed ~1.1ms of the 2.7ms wall is inter-launch gaps (~105
//    launches; the 7x12 pooling chain dominates). pool_all_k runs the ENTIRE
//    pooling loop in one cooperative launch with grid.sync() phase barriers;
//    each phase body is verbatim from the verified standalone kernels ->
//    bit-identical results. __launch_bounds__(256,4) + 1024 blocks keeps
//    4 blocks/CU co-resident. Fallback to the multi-kernel chain if the
//    cooperative launch is rejected.
//  * gemm200_k: 64-row tiles (782 blocks vs 391, VGPR ~75 vs 140) to fix
//    the 9% occupancy seen in round-2 counters. Per-element k-ascending
//    accumulation order unchanged -> bit-identical C.
//  * Keeps: epi fused in gat_out, edge_max fused in eeden, pk pack,
//    pool_agg+score fusion, depth-4 rolling pipelines.
// ---------------------------------------------------------------------------

__host__ __device__ inline void tf_round(uint32_t &x0, uint32_t &x1, int r) {
  x0 += x1;
  x1 = (x1 << r) | (x1 >> (32 - r));
  x1 ^= x0;
}

// Exact jax threefry2x32 (Random123 KAT: key(0,0),ctr(0,0) -> 6b200159 99ba4efe)
__host__ __device__ inline void threefry2x32(uint32_t k0, uint32_t k1,
                                             uint32_t &x0, uint32_t &x1) {
  uint32_t ks2 = k0 ^ k1 ^ 0x1BD11BDAu;
  x0 += k0; x1 += k1;
  tf_round(x0, x1, 13); tf_round(x0, x1, 15); tf_round(x0, x1, 26); tf_round(x0, x1, 6);
  x0 += k1; x1 += ks2 + 1u;
  tf_round(x0, x1, 17); tf_round(x0, x1, 29); tf_round(x0, x1, 16); tf_round(x0, x1, 24);
  x0 += ks2; x1 += k0 + 2u;
  tf_round(x0, x1, 13); tf_round(x0, x1, 15); tf_round(x0, x1, 26); tf_round(x0, x1, 6);
  x0 += k0; x1 += k1 + 3u;
  tf_round(x0, x1, 17); tf_round(x0, x1, 29); tf_round(x0, x1, 16); tf_round(x0, x1, 24);
  x0 += k1; x1 += ks2 + 4u;
  tf_round(x0, x1, 13); tf_round(x0, x1, 15); tf_round(x0, x1, 26); tf_round(x0, x1, 6);
  x0 += ks2; x1 += k0 + 5u;
}

// ---------------- GEMM: C[M x 200] = A[M x K] @ B[K x 200], fp32 -------------
// 64-row x 200-col tile, 256 threads; thread owns row r, col quarter
// colBase..colBase+51 (last quarter: 44 valid cols). Same per-element
// k-ascending FMA order as the previous 128-row version -> bit-identical.
__global__ __launch_bounds__(256) void gemm200_k(
    const float* __restrict__ A, const float* __restrict__ B,
    float* __restrict__ C, int M, int K) {
  __shared__ float As[64 * 9];                  // pad 8->9: conflict-free reads
  __shared__ __align__(16) float Bs[8][208];
  int tid = threadIdx.x;
  int m0 = blockIdx.x * 64;
  int r = tid >> 2;
  int colBase = (tid & 3) * 52;
  int nq = (colBase == 156) ? 11 : 13;          // valid float4s in epilogue
  float acc[52];
#pragma unroll
  for (int q = 0; q < 52; q++) acc[q] = 0.f;

  // staging assignments: A needs 64x8 = 512 floats = 128 float4 (tid<128)
  int arow = tid >> 1;
  int ac = (tid & 1) * 4;
  bool hasA = (tid < 128);
  int gmA = m0 + arow;
  const float* Aptr = A + (size_t)gmA * K + ac;
  int bk0 = tid / 50, bc0 = (tid - bk0 * 50) * 4;
  int t2 = tid + 256;
  int bk1 = t2 / 50, bc1 = (t2 - bk1 * 50) * 4;
  bool hasB1 = (t2 < 400);

  // prefetch tile 0 into registers
  float4 va = make_float4(0.f, 0.f, 0.f, 0.f);
  if (hasA && gmA < M) va = *(const float4*)(Aptr);
  float4 vb0 = *(const float4*)(B + (size_t)bk0 * 200 + bc0);
  float4 vb1 = make_float4(0.f, 0.f, 0.f, 0.f);
  if (hasB1) vb1 = *(const float4*)(B + (size_t)bk1 * 200 + bc1);

  for (int k0 = 0; k0 < K; k0 += 8) {
    if (hasA) {
      As[arow * 9 + ac + 0] = va.x;
      As[arow * 9 + ac + 1] = va.y;
      As[arow * 9 + ac + 2] = va.z;
      As[arow * 9 + ac + 3] = va.w;
    }
    *(float4*)(&Bs[bk0][bc0]) = vb0;
    if (hasB1) *(float4*)(&Bs[bk1][bc1]) = vb1;
    __syncthreads();
    int kn = k0 + 8;
    if (kn < K) {
      if (hasA && gmA < M) va = *(const float4*)(Aptr + kn);
      vb0 = *(const float4*)(B + (size_t)(kn + bk0) * 200 + bc0);
      if (hasB1) vb1 = *(const float4*)(B + (size_t)(kn + bk1) * 200 + bc1);
    }
#pragma unroll
    for (int kk = 0; kk < 8; kk++) {
      float a0 = As[r * 9 + kk];
#pragma unroll
      for (int q = 0; q < 13; q++) {
        float4 b = *(const float4*)(&Bs[kk][colBase + 4 * q]);
        acc[4 * q + 0] += a0 * b.x; acc[4 * q + 1] += a0 * b.y;
        acc[4 * q + 2] += a0 * b.z; acc[4 * q + 3] += a0 * b.w;
      }
    }
    __syncthreads();
  }
  int gm = m0 + r;
#pragma unroll
  for (int q = 0; q < 13; q++) {
    if (q < nq) {
      int col = colBase + 4 * q;
      float4 v0 = make_float4(acc[4 * q + 0], acc[4 * q + 1],
                              acc[4 * q + 2], acc[4 * q + 3]);
      if (gm < M) *(float4*)(C + (size_t)gm * 200 + col) = v0;
    }
  }
}

// ---------------- dual dot: o1[i]=H[i]·v1, o2[i]=H[i]·v2 (one wave/node) -----
__global__ __launch_bounds__(256) void dual_dot_k(
    const float* __restrict__ H, const float* __restrict__ v1,
    const float* __restrict__ v2, float* __restrict__ o1,
    float* __restrict__ o2, int n) {
  int wave = blockIdx.x * 4 + (threadIdx.x >> 6);
  int lane = threadIdx.x & 63;
  if (wave >= n) return;
  const float* row = H + (size_t)wave * 200;
  float s1 = 0.f, s2 = 0.f;
  for (int d = lane; d < 200; d += 64) {
    float h = row[d];
    s1 += h * v1[d];
    s2 += h * v2[d];
  }
  for (int off = 32; off; off >>= 1) {
    s1 += __shfl_down(s1, off);
    s2 += __shfl_down(s2, off);
  }
  if (lane == 0) { o1[wave] = s1; o2[wave] = s2; }
}

// ---------------- CSR build (dst-sorted, stable by edge index) ---------------
__global__ __launch_bounds__(256) void indeg_k(const int* __restrict__ dst,
                                               int* __restrict__ cnt, int E) {
  int e = blockIdx.x * 256 + threadIdx.x;
  if (e < E) atomicAdd(&cnt[dst[e]], 1);
}

// single block, 256 threads: exclusive scan cnt[0..N) -> rowptr[0..N]
__global__ __launch_bounds__(256) void scan_k(const int* __restrict__ cnt,
                                              int* __restrict__ rowptr, int N) {
  __shared__ int psum[256];
  int t = threadIdx.x;
  int CH = (N + 255) / 256;
  int beg = t * CH, end = min(beg + CH, N);
  if (beg > N) { beg = N; }
  int s = 0;
  for (int i = beg; i < end; i++) s += cnt[i];
  psum[t] = s;
  __syncthreads();
  if (t == 0) {
    int run = 0;
    for (int i = 0; i < 256; i++) { int v = psum[i]; psum[i] = run; run += v; }
  }
  __syncthreads();
  int run = psum[t];
  for (int i = beg; i < end; i++) { rowptr[i] = run; run += cnt[i]; }
  if (end == N && beg <= N) rowptr[N] = run;
}

__global__ __launch_bounds__(256) void cpyint_k(const int* __restrict__ a,
                                                int* __restrict__ b, int n) {
  int i = blockIdx.x * 256 + threadIdx.x;
  if (i < n) b[i] = a[i];
}

__global__ __launch_bounds__(256) void place_k(const int* __restrict__ dst,
                                               int* __restrict__ curs,
                                               int* __restrict__ csr, int E) {
  int e = blockIdx.x * 256 + threadIdx.x;
  if (e >= E) return;
  int pos = atomicAdd(&curs[dst[e]], 1);
  csr[pos] = e;
}

__global__ __launch_bounds__(256) void sortrow_k(const int* __restrict__ rowptr,
                                                 int* __restrict__ csr, int N) {
  int d = blockIdx.x * 256 + threadIdx.x;
  if (d >= N) return;
  int b = rowptr[d], e2 = rowptr[d + 1];
  for (int i = b + 1; i < e2; i++) {
    int v = csr[i];
    int j = i - 1;
    while (j >= b && csr[j] > v) { csr[j + 1] = csr[j]; j--; }
    csr[j + 1] = v;
  }
}

// ---------------- GAT edge softmax (deterministic, np order) -----------------
__device__ inline float dec_ord(unsigned enc) {
  unsigned b = (enc & 0x80000000u) ? (enc ^ 0x80000000u) : ~enc;
  return __uint_as_float(b);
}

__device__ inline unsigned enc_ord(float ev) {
  unsigned b = __float_as_uint(ev);
  return (b & 0x80000000u) ? ~b : (b | 0x80000000u);
}

// Fused max + ee + den + CSR-position pack (bit-identical to the old
// memset+atomicMax / ee_k / den_k chain; see round-12 comments).
__global__ __launch_bounds__(256) void eeden_k(
    const int* __restrict__ rowptr, const int* __restrict__ csr,
    const int* __restrict__ src, const float* __restrict__ as_,
    const float* __restrict__ ad_, int2* __restrict__ pk,
    float* __restrict__ eeS, float* __restrict__ den, int N) {
  int d = blockIdx.x * 256 + threadIdx.x;
  if (d >= N) return;
  float adv = ad_[d];
  int b = rowptr[d], e2 = rowptr[d + 1];
  unsigned mx = 0u;
  for (int i = b; i < e2; i++) {
    int sv = src[csr[i]];
    float v = as_[sv] + adv;
    float ev = (v >= 0.f) ? v : 0.2f * v;
    mx = max(mx, enc_ord(ev));
  }
  {
    float v = as_[d] + adv;  // self-loop term
    float ev = (v >= 0.f) ? v : 0.2f * v;
    mx = max(mx, enc_ord(ev));
  }
  float m = dec_ord(mx);
  float s = 0.f;
  for (int i = b; i < e2; i++) {
    int sv = src[csr[i]];
    float v = as_[sv] + adv;
    float ev = (v >= 0.f) ? v : 0.2f * v;
    float ee = expf(ev - m);
    pk[i] = make_int2(sv, __float_as_int(ee));
    s = __fadd_rn(s, ee);
  }
  float vS = as_[d] + adv;
  float evS = (vS >= 0.f) ? vS : 0.2f * vS;
  float eS = expf(evS - m);
  eeS[d] = eS;
  s = __fadd_rn(s, eS);
  den[d] = s;
}

#define GLD(s) (*(const float4*)(Hl + (size_t)(s) * 200))
#define ACC(W_, H_)                                    \
  acc.x = __fadd_rn(acc.x, __fmul_rn((W_), (H_).x));   \
  acc.y = __fadd_rn(acc.y, __fmul_rn((W_), (H_).y));   \
  acc.z = __fadd_rn(acc.z, __fmul_rn((W_), (H_).z));   \
  acc.w = __fadd_rn(acc.w, __fmul_rn((W_), (H_).w));

// GAT out + fused epilogue (bias/relu/threefry-dropout). See round-12/13.
__global__ __launch_bounds__(256) void gat_out_k(
    const int* __restrict__ rowptr, const int2* __restrict__ pk,
    const float* __restrict__ eeS, const float* __restrict__ den,
    const float* __restrict__ HW, const float* __restrict__ bias,
    float* __restrict__ OUT, uint32_t tk0, uint32_t tk1, int N) {
  int node = blockIdx.x * 4 + (threadIdx.x >> 6);
  int lane = threadIdx.x & 63;
  if (node >= N || lane >= 50) return;
  int b = rowptr[node];
  int deg = rowptr[node + 1] - b;
  int cnt = deg + 1;  // edges then self-loop (last)
  float dn = den[node];
  const float* __restrict__ Hl = HW + 4 * lane;

  auto fS = [&](int t, int &s, float &w) {
    if (t < deg) {
      int2 p = pk[b + t];
      s = p.x;
      w = __fdiv_rn(__int_as_float(p.y), dn);
    } else if (t == deg) {
      s = node;
      w = __fdiv_rn(eeS[node], dn);
    } else {
      s = node;  // cache-hot dummy row
      w = 0.f;
    }
  };

  int sa, sb, sc, sd, se, sf, sn;
  float w0, w1, w2, w3, w4, w5, wn;
  fS(0, sa, w0); fS(1, sb, w1); fS(2, sc, w2); fS(3, sd, w3);
  float4 h0 = GLD(sa), h1 = GLD(sb), h2 = GLD(sc), h3 = GLD(sd);
  fS(4, se, w4);
  fS(5, sf, w5);

  float4 acc = make_float4(0.f, 0.f, 0.f, 0.f);
  for (int t = 0; t < cnt; t++) {
    float4 h4 = GLD(se);
    fS(t + 6, sn, wn);
    ACC(w0, h0);
    h0 = h1; h1 = h2; h2 = h3; h3 = h4;
    w0 = w1; w1 = w2; w2 = w3; w3 = w4; w4 = w5; w5 = wn;
    se = sf; sf = sn;
  }

  // fused epi: per element j, exactly old epi_k's ops on the same value
  float4 bv4 = *(const float4*)(bias + 4 * lane);
  float vin[4] = {acc.x, acc.y, acc.z, acc.w};
  float bb4[4] = {bv4.x, bv4.y, bv4.z, bv4.w};
  float vout[4];
  int tbase = node * 200 + 4 * lane;
#pragma unroll
  for (int j = 0; j < 4; j++) {
    uint32_t x0 = 0u, x1 = (uint32_t)(tbase + j);
    threefry2x32(tk0, tk1, x0, x1);
    uint32_t bits = x0 ^ x1;
    float u = __uint_as_float((bits >> 9) | 0x3f800000u) - 1.0f;
    float v = vin[j] + bb4[j];
    v = fmaxf(v, 0.f);
    vout[j] = (u < 0.8f) ? (v / 0.8f) : 0.f;
  }
  *(float4*)(OUT + (size_t)node * 200 + 4 * lane) =
      make_float4(vout[0], vout[1], vout[2], vout[3]);
}

// ===================== COOPERATIVE POOLING MEGA-KERNEL =======================
// The full SAGPool loop (einit + 7x {agg+score, stable radix, gather, remap})
// in one launch; phase bodies are verbatim from the verified standalone
// kernels (same association / stable-sort semantics -> bit-identical).
__global__ __launch_bounds__(256, 4) void pool_all_k(
    const int* __restrict__ rowptr, const int* __restrict__ csr,
    const int* __restrict__ src, const int* __restrict__ dst,
    int* __restrict__ csrc, int* __restrict__ cdst,
    int* __restrict__ origA, int* __restrict__ origB,
    float* __restrict__ bufA, float* __restrict__ bufB,
    const float* __restrict__ wrel, const float* __restrict__ wroot,
    const float* __restrict__ bp, float* __restrict__ score,
    unsigned* __restrict__ keyA, unsigned* __restrict__ keyB,
    int* __restrict__ payA, int* __restrict__ payB,
    int* __restrict__ counts, int* __restrict__ base,
    int* __restrict__ perm, int* __restrict__ inv, int N, int E) {
  cg::grid_group gridg = cg::this_grid();
  __shared__ float sagg[4][200];
  __shared__ int ldsH[256];
  __shared__ int dig[256];
  int tid = threadIdx.x;
  int gsz = (int)gridDim.x;
  int wv = tid >> 6;
  int lane = tid & 63;

  // ---- einit ----
  for (int e = blockIdx.x * 256 + tid; e < E; e += gsz * 256) {
    csrc[e] = src[e];
    cdst[e] = dst[e];
  }
  for (int i = blockIdx.x * 256 + tid; i < N; i += gsz * 256) origA[i] = i;
  gridg.sync();

  float* hcur = bufB;
  float* hnext = bufA;
  int* ocur = origA;
  int* onext = origB;
  int n = N;
  while (true) {
    int k = (n + 1) / 2;
    int NB = (n + 255) / 256;

    // ---- phase: pool_agg + score (verbatim body) ----
    for (int u = blockIdx.x; u < (n + 3) / 4; u += gsz) {
      int node = u * 4 + wv;
      if (node < n) {
        int o = ocur[node];
        int b = rowptr[o];
        int deg = rowptr[o + 1] - b;
        if (lane < 50) {
          const float* __restrict__ Hl = hcur + 4 * lane;
          auto fS = [&](int t, int &s, float &w) {
            if (t < deg) {
              int e = csr[b + t];
              int sv = csrc[e];
              s = (sv >= 0) ? sv : 0;
              w = (sv >= 0) ? 1.f : 0.f;
            } else {
              s = 0;
              w = 0.f;
            }
          };
          int sa, sb, sc, sd, se, sf, sn;
          float w0, w1, w2, w3, w4, w5, wn;
          fS(0, sa, w0); fS(1, sb, w1); fS(2, sc, w2); fS(3, sd, w3);
          float4 h0 = GLD(sa), h1 = GLD(sb), h2 = GLD(sc), h3 = GLD(sd);
          fS(4, se, w4);
          fS(5, sf, w5);
          float4 acc = make_float4(0.f, 0.f, 0.f, 0.f);
          for (int t = 0; t < deg; t++) {
            float4 h4 = GLD(se);
            fS(t + 6, sn, wn);
            ACC(w0, h0);
            h0 = h1; h1 = h2; h2 = h3; h3 = h4;
            w0 = w1; w1 = w2; w2 = w3; w3 = w4; w4 = w5; w5 = wn;
            se = sf; sf = sn;
          }
          sagg[wv][4 * lane + 0] = acc.x;
          sagg[wv][4 * lane + 1] = acc.y;
          sagg[wv][4 * lane + 2] = acc.z;
          sagg[wv][4 * lane + 3] = acc.w;
        }
        __threadfence_block();
        const float* arow = sagg[wv];
        const float* hrow = hcur + (size_t)node * 200;
        float s1 = 0.f, s2 = 0.f;
        for (int d = lane; d < 200; d += 64) {
          s1 += arow[d] * wrel[d];
          s2 += hrow[d] * wroot[d];
        }
        for (int off = 32; off; off >>= 1) {
          s1 += __shfl_down(s1, off);
          s2 += __shfl_down(s2, off);
        }
        if (lane == 0) score[node] = tanhf((s1 + s2) + bp[0]);
      }
    }
    gridg.sync();

    // ---- phase: rhenc (encode + pass-0 histogram) ----
    for (int cb = blockIdx.x; cb < NB; cb += gsz) {
      ldsH[tid] = 0;
      __syncthreads();
      int i = cb * 256 + tid;
      if (i < n) {
        unsigned b = __float_as_uint(score[i]);
        if (b == 0x80000000u) b = 0u;  // -0 -> +0
        unsigned key = ~enc_ord(__uint_as_float(b));
        keyA[i] = key;
        payA[i] = i;
        atomicAdd(&ldsH[key & 255u], 1);
      }
      __syncthreads();
      counts[tid * NB + cb] = ldsH[tid];
      __syncthreads();
    }
    gridg.sync();

    unsigned* ki = keyA; unsigned* ko = keyB;
    int* pi = payA; int* po = payB;
    for (int pass = 0; pass < 4; pass++) {
      int shift = pass * 8;
      // ---- phase: scan (block 0) + zero counts ----
      if (blockIdx.x == 0) {
        int s = 0;
        for (int b = 0; b < NB; b++) s += counts[tid * NB + b];
        ldsH[tid] = s;
        __syncthreads();
        if (tid == 0) {
          int run = 0;
          for (int i = 0; i < 256; i++) { int v = ldsH[i]; ldsH[i] = run; run += v; }
        }
        __syncthreads();
        int run = ldsH[tid];
        for (int b = 0; b < NB; b++) {
          int c = counts[tid * NB + b];
          base[tid * NB + b] = run;
          run += c;
          counts[tid * NB + b] = 0;
        }
      }
      gridg.sync();
      // ---- phase: scatter ----
      if (pass < 3) {
        for (int cb = blockIdx.x; cb < NB; cb += gsz) {
          int i = cb * 256 + tid;
          unsigned kv = 0u;
          int pv = 0, d = -1;
          if (i < n) {
            kv = ki[i];
            pv = pi[i];
            d = (int)((kv >> shift) & 255u);
          }
          dig[tid] = d;
          __syncthreads();
          if (i < n) {
            int local = 0;
            for (int j = 0; j < tid; j++) local += (dig[j] == d) ? 1 : 0;
            int pos = base[d * NB + cb] + local;
            ko[pos] = kv;
            po[pos] = pv;
            atomicAdd(&counts[((kv >> (shift + 8)) & 255u) * NB + (pos >> 8)], 1);
          }
          __syncthreads();
        }
        { unsigned* t = ki; ki = ko; ko = t; }
        { int* t = pi; pi = po; po = t; }
      } else {
        // final pass: position IS the rank -> perm/inv/onext
        for (int cb = blockIdx.x; cb < NB; cb += gsz) {
          int i = cb * 256 + tid;
          int pv = 0, d = -1;
          if (i < n) {
            pv = pi[i];
            d = (int)((ki[i] >> 24) & 255u);
          }
          dig[tid] = d;
          __syncthreads();
          if (i < n) {
            int local = 0;
            for (int j = 0; j < tid; j++) local += (dig[j] == d) ? 1 : 0;
            int pos = base[d * NB + cb] + local;
            if (pos < k) { perm[pos] = pv; inv[pv] = pos; onext[pos] = ocur[pv]; }
            else inv[pv] = -1;
          }
          __syncthreads();
        }
      }
      gridg.sync();
    }

    // ---- phase: gather + remap ----
    int GU = k + (E + 255) / 256;
    for (int u = blockIdx.x; u < GU; u += gsz) {
      if (u < k) {
        int p = perm[u];
        float s = score[p];
        if (tid < 200)
          hnext[(size_t)u * 200 + tid] = __fmul_rn(hcur[(size_t)p * 200 + tid], s);
      } else {
        int e = (u - k) * 256 + tid;
        if (e < E) {
          int a = csrc[e];
          if (a >= 0) {
            int na = inv[a], nb = inv[cdst[e]];
            bool valid = (na >= 0) && (nb >= 0);
            csrc[e] = valid ? na : -1;
            cdst[e] = valid ? nb : -1;
          }
        }
      }
    }
    gridg.sync();

    { float* t = hcur; hcur = hnext; hnext = t; }
    { int* t = ocur; ocur = onext; onext = t; }
    n = k;
    if (n <= 512) break;
  }
}

// ---------------- fallback standalone pooling kernels (round-13 path) --------
__global__ __launch_bounds__(256) void einit_k(
    const int* __restrict__ src, const int* __restrict__ dst,
    int* __restrict__ cs, int* __restrict__ cd, int* __restrict__ orig,
    int E, int N) {
  int e = blockIdx.x * 256 + threadIdx.x;
  if (e < E) { cs[e] = src[e]; cd[e] = dst[e]; }
  if (e < N) orig[e] = e;
}

__global__ __launch_bounds__(256) void pool_agg_k(
    const int* __restrict__ rowptr, const int* __restrict__ csr,
    const int* __restrict__ csrc, const int* __restrict__ orig,
    const float* __restrict__ H, const float* __restrict__ wrel,
    const float* __restrict__ wroot, const float* __restrict__ bp,
    float* __restrict__ score, int n) {
  __shared__ float sagg[4][200];
  int wv = threadIdx.x >> 6;
  int node = blockIdx.x * 4 + wv;
  int lane = threadIdx.x & 63;
  if (node >= n) return;
  int o = orig[node];
  int b = rowptr[o];
  int deg = rowptr[o + 1] - b;
  if (lane < 50) {
    const float* __restrict__ Hl = H + 4 * lane;
    auto fS = [&](int t, int &s, float &w) {
      if (t < deg) {
        int e = csr[b + t];
        int sv = csrc[e];
        s = (sv >= 0) ? sv : 0;
        w = (sv >= 0) ? 1.f : 0.f;
      } else {
        s = 0;
        w = 0.f;
      }
    };
    int sa, sb, sc, sd, se, sf, sn;
    float w0, w1, w2, w3, w4, w5, wn;
    fS(0, sa, w0); fS(1, sb, w1); fS(2, sc, w2); fS(3, sd, w3);
    float4 h0 = GLD(sa), h1 = GLD(sb), h2 = GLD(sc), h3 = GLD(sd);
    fS(4, se, w4);
    fS(5, sf, w5);
    float4 acc = make_float4(0.f, 0.f, 0.f, 0.f);
    for (int t = 0; t < deg; t++) {
      float4 h4 = GLD(se);
      fS(t + 6, sn, wn);
      ACC(w0, h0);
      h0 = h1; h1 = h2; h2 = h3; h3 = h4;
      w0 = w1; w1 = w2; w2 = w3; w3 = w4; w4 = w5; w5 = wn;
      se = sf; sf = sn;
    }
    sagg[wv][4 * lane + 0] = acc.x;
    sagg[wv][4 * lane + 1] = acc.y;
    sagg[wv][4 * lane + 2] = acc.z;
    sagg[wv][4 * lane + 3] = acc.w;
  }
  __threadfence_block();
  const float* arow = sagg[wv];
  const float* hrow = H + (size_t)node * 200;
  float s1 = 0.f, s2 = 0.f;
  for (int d = lane; d < 200; d += 64) {
    s1 += arow[d] * wrel[d];
    s2 += hrow[d] * wroot[d];
  }
  for (int off = 32; off; off >>= 1) {
    s1 += __shfl_down(s1, off);
    s2 += __shfl_down(s2, off);
  }
  if (lane == 0) score[node] = tanhf((s1 + s2) + bp[0]);
}
#undef GLD
#undef ACC

__global__ __launch_bounds__(256) void rhenc_k(const float* __restrict__ score,
                                               unsigned* __restrict__ keyA,
                                               int* __restrict__ payA,
                                               int* __restrict__ counts,
                                               int n, int NB) {
  __shared__ int hist[256];
  hist[threadIdx.x] = 0;
  __syncthreads();
  int i = blockIdx.x * 256 + threadIdx.x;
  if (i < n) {
    unsigned b = __float_as_uint(score[i]);
    if (b == 0x80000000u) b = 0u;
    unsigned key = ~enc_ord(__uint_as_float(b));
    keyA[i] = key;
    payA[i] = i;
    atomicAdd(&hist[key & 255u], 1);
  }
  __syncthreads();
  counts[threadIdx.x * NB + blockIdx.x] = hist[threadIdx.x];
}

__global__ __launch_bounds__(256) void rscan_k(int* __restrict__ counts,
                                               int* __restrict__ base, int NB) {
  __shared__ int tot[256];
  int t = threadIdx.x;
  int s = 0;
  for (int b = 0; b < NB; b++) s += counts[t * NB + b];
  tot[t] = s;
  __syncthreads();
  if (t == 0) {
    int run = 0;
    for (int i = 0; i < 256; i++) { int v = tot[i]; tot[i] = run; run += v; }
  }
  __syncthreads();
  int run = tot[t];
  for (int b = 0; b < NB; b++) {
    int c = counts[t * NB + b];
    base[t * NB + b] = run;
    run += c;
    counts[t * NB + b] = 0;
  }
}

__global__ __launch_bounds__(256) void rscatter_k(
    const unsigned* __restrict__ keyIn, const int* __restrict__ payIn,
    const int* __restrict__ base, unsigned* __restrict__ keyOut,
    int* __restrict__ payOut, int* __restrict__ countsNext,
    int n, int NB, int shift) {
  __shared__ int dig[256];
  int t = threadIdx.x;
  int i = blockIdx.x * 256 + t;
  unsigned k = 0u;
  int p = 0, d = -1;
  if (i < n) {
    k = keyIn[i];
    p = payIn[i];
    d = (int)((k >> shift) & 255u);
  }
  dig[t] = d;
  __syncthreads();
  if (i < n) {
    int local = 0;
    for (int j = 0; j < t; j++) local += (dig[j] == d) ? 1 : 0;
    int pos = base[d * NB + blockIdx.x] + local;
    keyOut[pos] = k;
    payOut[pos] = p;
    atomicAdd(&countsNext[((k >> (shift + 8)) & 255u) * NB + (pos >> 8)], 1);
  }
}

__global__ __launch_bounds__(256) void rscatterF_k(
    const unsigned* __restrict__ keyIn, const int* __restrict__ payIn,
    const int* __restrict__ base, const int* __restrict__ oin,
    int* __restrict__ oout, int* __restrict__ perm, int* __restrict__ inv,
    int n, int NB, int k) {
  __shared__ int dig[256];
  int t = threadIdx.x;
  int i = blockIdx.x * 256 + t;
  int p = 0, d = -1;
  if (i < n) {
    p = payIn[i];
    d = (int)((keyIn[i] >> 24) & 255u);
  }
  dig[t] = d;
  __syncthreads();
  if (i < n) {
    int local = 0;
    for (int j = 0; j < t; j++) local += (dig[j] == d) ? 1 : 0;
    int pos = base[d * NB + blockIdx.x] + local;
    if (pos < k) { perm[pos] = p; inv[p] = pos; oout[pos] = oin[p]; }
    else inv[p] = -1;
  }
}

__global__ __launch_bounds__(256) void gather_k(
    const float* __restrict__ H, const int* __restrict__ perm,
    const float* __restrict__ score, float* __restrict__ Ho, int k) {
  int r = blockIdx.x;
  int d = threadIdx.x;
  int p = perm[r];
  float s = score[p];
  if (d < 200) Ho[(size_t)r * 200 + d] = __fmul_rn(H[(size_t)p * 200 + d], s);
}

__global__ __launch_bounds__(256) void remap_k(int* __restrict__ cs,
                                               int* __restrict__ cd,
                                               const int* __restrict__ inv, int E) {
  int e = blockIdx.x * 256 + threadIdx.x;
  if (e >= E) return;
  int a = cs[e];
  if (a < 0) return;
  int na = inv[a], nb = inv[cd[e]];
  bool valid = (na >= 0) && (nb >= 0);
  cs[e] = valid ? na : -1;
  cd[e] = valid ? nb : -1;
}

__global__ __launch_bounds__(256) void out_copy_k(const float* __restrict__ h,
                                                  float* __restrict__ out, int cnt) {
  int t = blockIdx.x * 256 + threadIdx.x;
  if (t < cnt) out[t] = h[t];
}

// ---------------------------------------------------------------------------
extern "C" void kernel_launch(void* const* d_in, const int* in_sizes, int n_in,
                              void* d_out, int out_size, void* d_ws, size_t ws_size,
                              hipStream_t stream) {
  const int ID = 128, HD = 200;
  const int N = in_sizes[0] / ID;   // 50000
  const int E = in_sizes[1];        // 800000

  const float* x = (const float*)d_in[0];
  const int* src = (const int*)d_in[1];
  const int* dst = (const int*)d_in[2];
  const float* W[3]   = {(const float*)d_in[3], (const float*)d_in[7], (const float*)d_in[11]};
  const float* asv[3] = {(const float*)d_in[4], (const float*)d_in[8], (const float*)d_in[12]};
  const float* adv[3] = {(const float*)d_in[5], (const float*)d_in[9], (const float*)d_in[13]};
  const float* bv[3]  = {(const float*)d_in[6], (const float*)d_in[10], (const float*)d_in[14]};
  const float* Wrel  = (const float*)d_in[15];
  const float* Wroot = (const float*)d_in[16];
  const float* bpool = (const float*)d_in[17];

  char* ws = (char*)d_ws;
  float*    bufA  = (float*)(ws + 0);           // 40,000,000
  float*    bufB  = (float*)(ws + 40000000);    // 40,000,000
  float*    as_   = (float*)(ws + 80000000);    //   200,000
  float*    ad_   = (float*)(ws + 80200000);    //   200,000
  // ee_ region (3.4MB): GAT phase -> eeS; pooling phase -> radix scratch
  float*    den   = (float*)(ws + 84000000);    //   200,000
  float*    score = (float*)(ws + 84200000);    //   200,000
  int*      rank_ = (int*)(ws + 84400000);      //   200,000 (CSR count scratch)
  int*      perm_ = (int*)(ws + 84600000);      //   200,000
  int*      inv_  = (int*)(ws + 84800000);      //   200,000
  int*      origA = (int*)(ws + 85000000);      //   200,000
  int*      origB = (int*)(ws + 85200000);      //   200,000
  int*      rowptr= (int*)(ws + 85400000);      //   250,000 (N+1 ints)
  int*      curs  = (int*)(ws + 85650000);      //   200,000
  int*      csr   = (int*)(ws + 85850000);      // 3,200,000
  int*      csrc  = (int*)(ws + 89050000);      // 3,200,000
  int*      cdst  = (int*)(ws + 92250000);      // 3,200,000  -> total 95.45 MB

  int2* pk = (int2*)(ws + 89050000);     // GAT-phase reuse of csrc+cdst
  float* eeS = (float*)(ws + 80400000);  // GAT-phase reuse of ee_ region

  char* rx = ws + 80400000;              // pooling-phase radix scratch
  unsigned* keyA   = (unsigned*)(rx + 0 * 262144);
  unsigned* keyB   = (unsigned*)(rx + 1 * 262144);
  int*      payA   = (int*)(rx + 2 * 262144);
  int*      payB   = (int*)(rx + 3 * 262144);
  int*      rcounts= (int*)(rx + 4 * 262144);
  int*      rbase  = (int*)(rx + 5 * 262144);

  // Host-side fold_in(key(42), i) = threefry2x32(k=(0,42), x=(0,i)).
  uint32_t fk0[3], fk1[3];
  for (int i = 0; i < 3; i++) {
    uint32_t a = 0u, b = (uint32_t)i;
    threefry2x32(0u, 42u, a, b);
    fk0[i] = a; fk1[i] = b;
  }

  const int B256 = 256;
  // ---------------- CSR build (once) ----------------
  hipMemsetAsync(rank_, 0, (size_t)N * 4, stream);
  indeg_k<<<(E + 255) / 256, B256, 0, stream>>>(dst, rank_, E);
  scan_k<<<1, B256, 0, stream>>>(rank_, rowptr, N);
  cpyint_k<<<(N + 255) / 256, B256, 0, stream>>>(rowptr, curs, N);
  place_k<<<(E + 255) / 256, B256, 0, stream>>>(dst, curs, csr, E);
  sortrow_k<<<(N + 255) / 256, B256, 0, stream>>>(rowptr, csr, N);

  // ---------------- 3 GAT layers ----------------
  for (int i = 0; i < 3; i++) {
    const float* in = (i == 0) ? x : bufB;
    int K = (i == 0) ? ID : HD;
    gemm200_k<<<(N + 63) / 64, B256, 0, stream>>>(in, W[i], bufA, N, K);
    dual_dot_k<<<(N + 3) / 4, B256, 0, stream>>>(bufA, asv[i], adv[i], as_, ad_, N);
    eeden_k<<<(N + 255) / 256, B256, 0, stream>>>(rowptr, csr, src, as_, ad_,
                                                  pk, eeS, den, N);
    gat_out_k<<<(N + 3) / 4, B256, 0, stream>>>(rowptr, pk, eeS, den, bufA,
                                                bv[i], bufB, fk0[i], fk1[i], N);
  }

  // ---------------- SAGPooling: single cooperative launch ----------------
  int N_ = N, E_ = E;
  void* cargs[] = {
      (void*)&rowptr, (void*)&csr, (void*)&src, (void*)&dst,
      (void*)&csrc, (void*)&cdst, (void*)&origA, (void*)&origB,
      (void*)&bufA, (void*)&bufB, (void*)&Wrel, (void*)&Wroot,
      (void*)&bpool, (void*)&score, (void*)&keyA, (void*)&keyB,
      (void*)&payA, (void*)&payB, (void*)&rcounts, (void*)&rbase,
      (void*)&perm_, (void*)&inv_, (void*)&N_, (void*)&E_};
  int maxb = 0;
  hipError_t occ_err = hipOccupancyMaxActiveBlocksPerMultiprocessor(
      &maxb, (const void*)pool_all_k, 256, 0);
  if (occ_err != hipSuccess || maxb < 1) maxb = 1;
  int coop_grid = maxb * 256;  // 256 CUs
  if (coop_grid > 1024) coop_grid = 1024;
  hipError_t coop_err = hipLaunchCooperativeKernel(
      (const void*)pool_all_k, dim3(coop_grid), dim3(B256), cargs, 0, stream);

  // compute final buffer / n (host mirrors the device loop)
  int n = N, swaps = 0;
  while (true) { n = (n + 1) / 2; swaps++; if (n <= 512) break; }
  float* hfinal = (swaps & 1) ? bufA : bufB;

  if (coop_err != hipSuccess) {
    // -------- fallback: round-13 multi-kernel pooling chain --------
    einit_k<<<(E + 255) / 256, B256, 0, stream>>>(src, dst, csrc, cdst, origA, E, N);
    float* hcur = bufB; float* hnext = bufA;
    int* ocur = origA; int* onext = origB;
    int nn = N;
    while (true) {
      int k = (nn + 1) / 2;
      int NB = (nn + 255) / 256;
      pool_agg_k<<<(nn + 3) / 4, B256, 0, stream>>>(rowptr, csr, csrc, ocur, hcur,
                                                    Wrel, Wroot, bpool, score, nn);
      rhenc_k<<<NB, B256, 0, stream>>>(score, keyA, payA, rcounts, nn, NB);
      rscan_k<<<1, B256, 0, stream>>>(rcounts, rbase, NB);
      rscatter_k<<<NB, B256, 0, stream>>>(keyA, payA, rbase, keyB, payB, rcounts, nn, NB, 0);
      rscan_k<<<1, B256, 0, stream>>>(rcounts, rbase, NB);
      rscatter_k<<<NB, B256, 0, stream>>>(keyB, payB, rbase, keyA, payA, rcounts, nn, NB, 8);
      rscan_k<<<1, B256, 0, stream>>>(rcounts, rbase, NB);
      rscatter_k<<<NB, B256, 0, stream>>>(keyA, payA, rbase, keyB, payB, rcounts, nn, NB, 16);
      rscan_k<<<1, B256, 0, stream>>>(rcounts, rbase, NB);
      rscatterF_k<<<NB, B256, 0, stream>>>(keyB, payB, rbase, ocur, onext, perm_, inv_,
                                           nn, NB, k);
      gather_k<<<k, B256, 0, stream>>>(hcur, perm_, score, hnext, k);
      remap_k<<<(E + 255) / 256, B256, 0, stream>>>(csrc, cdst, inv_, E);
      { float* t = hcur; hcur = hnext; hnext = t; }
      { int* t = ocur; ocur = onext; onext = t; }
      nn = k;
      if (nn <= 512) break;
    }
    hfinal = hcur;
    n = nn;
  }

  // ---------------- output: zeros(512,200) with first n rows = h -------------
  hipMemsetAsync(d_out, 0, (size_t)out_size * 4, stream);
  out_copy_k<<<(n * HD + 255) / 256, B256, 0, stream>>>(hfinal, (float*)d_out, n * HD);
}

// Round 11
// 2762.825 us; speedup vs baseline: 3.3099x; 3.3099x over previous
//
#include <hip/hip_runtime.h>
#include <cstdint>
#include <cstddef>

// ---------------------------------------------------------------------------
// GAT x3 (exact JAX-threefry dropout, PARTITIONABLE mode) + SAGPool x7.
// Round 15 = Round 13 structure (multi-kernel pooling; cooperative grid.sync
// costs ~130us/sync on MI355X's non-coherent XCD L2s -> abandoned) plus:
//  * 64-row gemm tile (bitwise-verified in round 14; occupancy 2x).
//  * gr_k: gather+remap fused in one launch (bodies verbatim).
//  * scan_k emits curs directly (-cpyint); out_copy_k zero-fills (-memset).
// Keeps: epi fused in gat_out, edge_max fused in eeden, pk pack,
// pool_agg+score fusion, depth-4 rolling pipelines, stable 4x8 LSD radix.
// All segment ops deterministic + np-association-matched (CSR serial).
// ---------------------------------------------------------------------------

__host__ __device__ inline void tf_round(uint32_t &x0, uint32_t &x1, int r) {
  x0 += x1;
  x1 = (x1 << r) | (x1 >> (32 - r));
  x1 ^= x0;
}

// Exact jax threefry2x32 (Random123 KAT: key(0,0),ctr(0,0) -> 6b200159 99ba4efe)
__host__ __device__ inline void threefry2x32(uint32_t k0, uint32_t k1,
                                             uint32_t &x0, uint32_t &x1) {
  uint32_t ks2 = k0 ^ k1 ^ 0x1BD11BDAu;
  x0 += k0; x1 += k1;
  tf_round(x0, x1, 13); tf_round(x0, x1, 15); tf_round(x0, x1, 26); tf_round(x0, x1, 6);
  x0 += k1; x1 += ks2 + 1u;
  tf_round(x0, x1, 17); tf_round(x0, x1, 29); tf_round(x0, x1, 16); tf_round(x0, x1, 24);
  x0 += ks2; x1 += k0 + 2u;
  tf_round(x0, x1, 13); tf_round(x0, x1, 15); tf_round(x0, x1, 26); tf_round(x0, x1, 6);
  x0 += k0; x1 += k1 + 3u;
  tf_round(x0, x1, 17); tf_round(x0, x1, 29); tf_round(x0, x1, 16); tf_round(x0, x1, 24);
  x0 += k1; x1 += ks2 + 4u;
  tf_round(x0, x1, 13); tf_round(x0, x1, 15); tf_round(x0, x1, 26); tf_round(x0, x1, 6);
  x0 += ks2; x1 += k0 + 5u;
}

// ---------------- GEMM: C[M x 200] = A[M x K] @ B[K x 200], fp32 -------------
// 64-row x 200-col tile, 256 threads; thread owns row r, col quarter.
// Per-element k-ascending FMA order identical to the 128-row version
// (bitwise-verified end-to-end in round 14).
__global__ __launch_bounds__(256) void gemm200_k(
    const float* __restrict__ A, const float* __restrict__ B,
    float* __restrict__ C, int M, int K) {
  __shared__ float As[64 * 9];                  // pad 8->9: conflict-free reads
  __shared__ __align__(16) float Bs[8][208];
  int tid = threadIdx.x;
  int m0 = blockIdx.x * 64;
  int r = tid >> 2;
  int colBase = (tid & 3) * 52;
  int nq = (colBase == 156) ? 11 : 13;          // valid float4s in epilogue
  float acc[52];
#pragma unroll
  for (int q = 0; q < 52; q++) acc[q] = 0.f;

  int arow = tid >> 1;
  int ac = (tid & 1) * 4;
  bool hasA = (tid < 128);
  int gmA = m0 + arow;
  const float* Aptr = A + (size_t)gmA * K + ac;
  int bk0 = tid / 50, bc0 = (tid - bk0 * 50) * 4;
  int t2 = tid + 256;
  int bk1 = t2 / 50, bc1 = (t2 - bk1 * 50) * 4;
  bool hasB1 = (t2 < 400);

  float4 va = make_float4(0.f, 0.f, 0.f, 0.f);
  if (hasA && gmA < M) va = *(const float4*)(Aptr);
  float4 vb0 = *(const float4*)(B + (size_t)bk0 * 200 + bc0);
  float4 vb1 = make_float4(0.f, 0.f, 0.f, 0.f);
  if (hasB1) vb1 = *(const float4*)(B + (size_t)bk1 * 200 + bc1);

  for (int k0 = 0; k0 < K; k0 += 8) {
    if (hasA) {
      As[arow * 9 + ac + 0] = va.x;
      As[arow * 9 + ac + 1] = va.y;
      As[arow * 9 + ac + 2] = va.z;
      As[arow * 9 + ac + 3] = va.w;
    }
    *(float4*)(&Bs[bk0][bc0]) = vb0;
    if (hasB1) *(float4*)(&Bs[bk1][bc1]) = vb1;
    __syncthreads();
    int kn = k0 + 8;
    if (kn < K) {
      if (hasA && gmA < M) va = *(const float4*)(Aptr + kn);
      vb0 = *(const float4*)(B + (size_t)(kn + bk0) * 200 + bc0);
      if (hasB1) vb1 = *(const float4*)(B + (size_t)(kn + bk1) * 200 + bc1);
    }
#pragma unroll
    for (int kk = 0; kk < 8; kk++) {
      float a0 = As[r * 9 + kk];
#pragma unroll
      for (int q = 0; q < 13; q++) {
        float4 b = *(const float4*)(&Bs[kk][colBase + 4 * q]);
        acc[4 * q + 0] += a0 * b.x; acc[4 * q + 1] += a0 * b.y;
        acc[4 * q + 2] += a0 * b.z; acc[4 * q + 3] += a0 * b.w;
      }
    }
    __syncthreads();
  }
  int gm = m0 + r;
#pragma unroll
  for (int q = 0; q < 13; q++) {
    if (q < nq) {
      int col = colBase + 4 * q;
      float4 v0 = make_float4(acc[4 * q + 0], acc[4 * q + 1],
                              acc[4 * q + 2], acc[4 * q + 3]);
      if (gm < M) *(float4*)(C + (size_t)gm * 200 + col) = v0;
    }
  }
}

// ---------------- dual dot: o1[i]=H[i]·v1, o2[i]=H[i]·v2 (one wave/node) -----
__global__ __launch_bounds__(256) void dual_dot_k(
    const float* __restrict__ H, const float* __restrict__ v1,
    const float* __restrict__ v2, float* __restrict__ o1,
    float* __restrict__ o2, int n) {
  int wave = blockIdx.x * 4 + (threadIdx.x >> 6);
  int lane = threadIdx.x & 63;
  if (wave >= n) return;
  const float* row = H + (size_t)wave * 200;
  float s1 = 0.f, s2 = 0.f;
  for (int d = lane; d < 200; d += 64) {
    float h = row[d];
    s1 += h * v1[d];
    s2 += h * v2[d];
  }
  for (int off = 32; off; off >>= 1) {
    s1 += __shfl_down(s1, off);
    s2 += __shfl_down(s2, off);
  }
  if (lane == 0) { o1[wave] = s1; o2[wave] = s2; }
}

// ---------------- CSR build (dst-sorted, stable by edge index) ---------------
__global__ __launch_bounds__(256) void indeg_k(const int* __restrict__ dst,
                                               int* __restrict__ cnt, int E) {
  int e = blockIdx.x * 256 + threadIdx.x;
  if (e < E) atomicAdd(&cnt[dst[e]], 1);
}

// single block, 256 threads: exclusive scan cnt[0..N) -> rowptr[0..N] + curs
__global__ __launch_bounds__(256) void scan_k(const int* __restrict__ cnt,
                                              int* __restrict__ rowptr,
                                              int* __restrict__ curs, int N) {
  __shared__ int psum[256];
  int t = threadIdx.x;
  int CH = (N + 255) / 256;
  int beg = t * CH, end = min(beg + CH, N);
  if (beg > N) { beg = N; }
  int s = 0;
  for (int i = beg; i < end; i++) s += cnt[i];
  psum[t] = s;
  __syncthreads();
  if (t == 0) {
    int run = 0;
    for (int i = 0; i < 256; i++) { int v = psum[i]; psum[i] = run; run += v; }
  }
  __syncthreads();
  int run = psum[t];
  for (int i = beg; i < end; i++) {
    rowptr[i] = run;
    curs[i] = run;
    run += cnt[i];
  }
  if (end == N && beg <= N) rowptr[N] = run;
}

__global__ __launch_bounds__(256) void place_k(const int* __restrict__ dst,
                                               int* __restrict__ curs,
                                               int* __restrict__ csr, int E) {
  int e = blockIdx.x * 256 + threadIdx.x;
  if (e >= E) return;
  int pos = atomicAdd(&curs[dst[e]], 1);
  csr[pos] = e;
}

__global__ __launch_bounds__(256) void sortrow_k(const int* __restrict__ rowptr,
                                                 int* __restrict__ csr, int N) {
  int d = blockIdx.x * 256 + threadIdx.x;
  if (d >= N) return;
  int b = rowptr[d], e2 = rowptr[d + 1];
  for (int i = b + 1; i < e2; i++) {
    int v = csr[i];
    int j = i - 1;
    while (j >= b && csr[j] > v) { csr[j + 1] = csr[j]; j--; }
    csr[j + 1] = v;
  }
}

// ---------------- GAT edge softmax (deterministic, np order) -----------------
__device__ inline float dec_ord(unsigned enc) {
  unsigned b = (enc & 0x80000000u) ? (enc ^ 0x80000000u) : ~enc;
  return __uint_as_float(b);
}

__device__ inline unsigned enc_ord(float ev) {
  unsigned b = __float_as_uint(ev);
  return (b & 0x80000000u) ? ~b : (b | 0x80000000u);
}

// Fused max + ee + den + CSR-position pack (bit-identical to the old
// memset+atomicMax / ee_k / den_k chain; see round-12 comments).
__global__ __launch_bounds__(256) void eeden_k(
    const int* __restrict__ rowptr, const int* __restrict__ csr,
    const int* __restrict__ src, const float* __restrict__ as_,
    const float* __restrict__ ad_, int2* __restrict__ pk,
    float* __restrict__ eeS, float* __restrict__ den, int N) {
  int d = blockIdx.x * 256 + threadIdx.x;
  if (d >= N) return;
  float adv = ad_[d];
  int b = rowptr[d], e2 = rowptr[d + 1];
  unsigned mx = 0u;
  for (int i = b; i < e2; i++) {
    int sv = src[csr[i]];
    float v = as_[sv] + adv;
    float ev = (v >= 0.f) ? v : 0.2f * v;
    mx = max(mx, enc_ord(ev));
  }
  {
    float v = as_[d] + adv;  // self-loop term
    float ev = (v >= 0.f) ? v : 0.2f * v;
    mx = max(mx, enc_ord(ev));
  }
  float m = dec_ord(mx);
  float s = 0.f;
  for (int i = b; i < e2; i++) {
    int sv = src[csr[i]];
    float v = as_[sv] + adv;
    float ev = (v >= 0.f) ? v : 0.2f * v;
    float ee = expf(ev - m);
    pk[i] = make_int2(sv, __float_as_int(ee));
    s = __fadd_rn(s, ee);
  }
  float vS = as_[d] + adv;
  float evS = (vS >= 0.f) ? vS : 0.2f * vS;
  float eS = expf(evS - m);
  eeS[d] = eS;
  s = __fadd_rn(s, eS);
  den[d] = s;
}

#define GLD(s) (*(const float4*)(Hl + (size_t)(s) * 200))
#define ACC(W_, H_)                                    \
  acc.x = __fadd_rn(acc.x, __fmul_rn((W_), (H_).x));   \
  acc.y = __fadd_rn(acc.y, __fmul_rn((W_), (H_).y));   \
  acc.z = __fadd_rn(acc.z, __fmul_rn((W_), (H_).z));   \
  acc.w = __fadd_rn(acc.w, __fmul_rn((W_), (H_).w));

// GAT out + fused epilogue (bias/relu/threefry-dropout, bitwise = old epi_k;
// threefry counter t = node*200+col). Wave per node, serial over edges
// (edge-index order, self last). Depth-4 rolling pipeline; per edge ONE
// contiguous 8B pk load. w = __fdiv_rn(ee,den) is bitwise alpha_k's division.
// Pad slots read the node's own cache-hot row with w=0 -> exact FP no-ops.
__global__ __launch_bounds__(256) void gat_out_k(
    const int* __restrict__ rowptr, const int2* __restrict__ pk,
    const float* __restrict__ eeS, const float* __restrict__ den,
    const float* __restrict__ HW, const float* __restrict__ bias,
    float* __restrict__ OUT, uint32_t tk0, uint32_t tk1, int N) {
  int node = blockIdx.x * 4 + (threadIdx.x >> 6);
  int lane = threadIdx.x & 63;
  if (node >= N || lane >= 50) return;
  int b = rowptr[node];
  int deg = rowptr[node + 1] - b;
  int cnt = deg + 1;  // edges then self-loop (last)
  float dn = den[node];
  const float* __restrict__ Hl = HW + 4 * lane;

  auto fS = [&](int t, int &s, float &w) {
    if (t < deg) {
      int2 p = pk[b + t];
      s = p.x;
      w = __fdiv_rn(__int_as_float(p.y), dn);
    } else if (t == deg) {
      s = node;
      w = __fdiv_rn(eeS[node], dn);
    } else {
      s = node;  // cache-hot dummy row
      w = 0.f;
    }
  };

  int sa, sb, sc, sd, se, sf, sn;
  float w0, w1, w2, w3, w4, w5, wn;
  fS(0, sa, w0); fS(1, sb, w1); fS(2, sc, w2); fS(3, sd, w3);
  float4 h0 = GLD(sa), h1 = GLD(sb), h2 = GLD(sc), h3 = GLD(sd);
  fS(4, se, w4);
  fS(5, sf, w5);

  float4 acc = make_float4(0.f, 0.f, 0.f, 0.f);
  for (int t = 0; t < cnt; t++) {
    float4 h4 = GLD(se);
    fS(t + 6, sn, wn);
    ACC(w0, h0);
    h0 = h1; h1 = h2; h2 = h3; h3 = h4;
    w0 = w1; w1 = w2; w2 = w3; w3 = w4; w4 = w5; w5 = wn;
    se = sf; sf = sn;
  }

  // fused epi: per element j, exactly old epi_k's ops on the same value
  float4 bv4 = *(const float4*)(bias + 4 * lane);
  float vin[4] = {acc.x, acc.y, acc.z, acc.w};
  float bb4[4] = {bv4.x, bv4.y, bv4.z, bv4.w};
  float vout[4];
  int tbase = node * 200 + 4 * lane;
#pragma unroll
  for (int j = 0; j < 4; j++) {
    uint32_t x0 = 0u, x1 = (uint32_t)(tbase + j);
    threefry2x32(tk0, tk1, x0, x1);
    uint32_t bits = x0 ^ x1;
    float u = __uint_as_float((bits >> 9) | 0x3f800000u) - 1.0f;
    float v = vin[j] + bb4[j];
    v = fmaxf(v, 0.f);
    vout[j] = (u < 0.8f) ? (v / 0.8f) : 0.f;
  }
  *(float4*)(OUT + (size_t)node * 200 + 4 * lane) =
      make_float4(vout[0], vout[1], vout[2], vout[3]);
}

// ---------------- pooling kernels -------------------------------------------
__global__ __launch_bounds__(256) void einit_k(
    const int* __restrict__ src, const int* __restrict__ dst,
    int* __restrict__ cs, int* __restrict__ cd, int* __restrict__ orig,
    int E, int N) {
  int e = blockIdx.x * 256 + threadIdx.x;
  if (e < E) { cs[e] = src[e]; cd[e] = dst[e]; }
  if (e < N) orig[e] = e;
}

// Fused pool_agg + score (exact summation order + shfl tree; see round-11).
__global__ __launch_bounds__(256) void pool_agg_k(
    const int* __restrict__ rowptr, const int* __restrict__ csr,
    const int* __restrict__ csrc, const int* __restrict__ orig,
    const float* __restrict__ H, const float* __restrict__ wrel,
    const float* __restrict__ wroot, const float* __restrict__ bp,
    float* __restrict__ score, int n) {
  __shared__ float sagg[4][200];
  int wv = threadIdx.x >> 6;
  int node = blockIdx.x * 4 + wv;
  int lane = threadIdx.x & 63;
  if (node >= n) return;
  int o = orig[node];
  int b = rowptr[o];
  int deg = rowptr[o + 1] - b;
  if (lane < 50) {
    const float* __restrict__ Hl = H + 4 * lane;
    auto fS = [&](int t, int &s, float &w) {
      if (t < deg) {
        int e = csr[b + t];
        int sv = csrc[e];
        s = (sv >= 0) ? sv : 0;
        w = (sv >= 0) ? 1.f : 0.f;
      } else {
        s = 0;
        w = 0.f;
      }
    };
    int sa, sb, sc, sd, se, sf, sn;
    float w0, w1, w2, w3, w4, w5, wn;
    fS(0, sa, w0); fS(1, sb, w1); fS(2, sc, w2); fS(3, sd, w3);
    float4 h0 = GLD(sa), h1 = GLD(sb), h2 = GLD(sc), h3 = GLD(sd);
    fS(4, se, w4);
    fS(5, sf, w5);
    float4 acc = make_float4(0.f, 0.f, 0.f, 0.f);
    for (int t = 0; t < deg; t++) {
      float4 h4 = GLD(se);
      fS(t + 6, sn, wn);
      ACC(w0, h0);
      h0 = h1; h1 = h2; h2 = h3; h3 = h4;
      w0 = w1; w1 = w2; w2 = w3; w3 = w4; w4 = w5; w5 = wn;
      se = sf; sf = sn;
    }
    sagg[wv][4 * lane + 0] = acc.x;
    sagg[wv][4 * lane + 1] = acc.y;
    sagg[wv][4 * lane + 2] = acc.z;
    sagg[wv][4 * lane + 3] = acc.w;
  }
  __threadfence_block();
  const float* arow = sagg[wv];
  const float* hrow = H + (size_t)node * 200;
  float s1 = 0.f, s2 = 0.f;
  for (int d = lane; d < 200; d += 64) {
    s1 += arow[d] * wrel[d];
    s2 += hrow[d] * wroot[d];
  }
  for (int off = 32; off; off >>= 1) {
    s1 += __shfl_down(s1, off);
    s2 += __shfl_down(s2, off);
  }
  if (lane == 0) score[node] = tanhf((s1 + s2) + bp[0]);
}
#undef GLD
#undef ACC

// ---------------- stable LSD radix sort -> exact lax.top_k rank --------------
// pass-0: encode key + write key/pay + histogram digit 0
__global__ __launch_bounds__(256) void rhenc_k(const float* __restrict__ score,
                                               unsigned* __restrict__ keyA,
                                               int* __restrict__ payA,
                                               int* __restrict__ counts,
                                               int n, int NB) {
  __shared__ int hist[256];
  hist[threadIdx.x] = 0;
  __syncthreads();
  int i = blockIdx.x * 256 + threadIdx.x;
  if (i < n) {
    unsigned b = __float_as_uint(score[i]);
    if (b == 0x80000000u) b = 0u;  // -0 -> +0
    unsigned key = ~enc_ord(__uint_as_float(b));
    keyA[i] = key;
    payA[i] = i;
    atomicAdd(&hist[key & 255u], 1);
  }
  __syncthreads();
  counts[threadIdx.x * NB + blockIdx.x] = hist[threadIdx.x];
}

// single block: exclusive scan (digit-major, block-minor) + zero counts
__global__ __launch_bounds__(256) void rscan_k(int* __restrict__ counts,
                                               int* __restrict__ base, int NB) {
  __shared__ int tot[256];
  int t = threadIdx.x;
  int s = 0;
  for (int b = 0; b < NB; b++) s += counts[t * NB + b];
  tot[t] = s;
  __syncthreads();
  if (t == 0) {
    int run = 0;
    for (int i = 0; i < 256; i++) { int v = tot[i]; tot[i] = run; run += v; }
  }
  __syncthreads();
  int run = tot[t];
  for (int b = 0; b < NB; b++) {
    int c = counts[t * NB + b];
    base[t * NB + b] = run;
    run += c;
    counts[t * NB + b] = 0;  // ready for next pass's fused histogram
  }
}

// stable scatter + fused next-pass histogram
__global__ __launch_bounds__(256) void rscatter_k(
    const unsigned* __restrict__ keyIn, const int* __restrict__ payIn,
    const int* __restrict__ base, unsigned* __restrict__ keyOut,
    int* __restrict__ payOut, int* __restrict__ countsNext,
    int n, int NB, int shift) {
  __shared__ int dig[256];
  int t = threadIdx.x;
  int i = blockIdx.x * 256 + t;
  unsigned k = 0u;
  int p = 0, d = -1;
  if (i < n) {
    k = keyIn[i];
    p = payIn[i];
    d = (int)((k >> shift) & 255u);
  }
  dig[t] = d;
  __syncthreads();
  if (i < n) {
    int local = 0;
    for (int j = 0; j < t; j++) local += (dig[j] == d) ? 1 : 0;
    int pos = base[d * NB + blockIdx.x] + local;
    keyOut[pos] = k;
    payOut[pos] = p;
    atomicAdd(&countsNext[((k >> (shift + 8)) & 255u) * NB + (pos >> 8)], 1);
  }
}

// final pass (shift=24): scatter position IS the rank -> perm/inv/oout
__global__ __launch_bounds__(256) void rscatterF_k(
    const unsigned* __restrict__ keyIn, const int* __restrict__ payIn,
    const int* __restrict__ base, const int* __restrict__ oin,
    int* __restrict__ oout, int* __restrict__ perm, int* __restrict__ inv,
    int n, int NB, int k) {
  __shared__ int dig[256];
  int t = threadIdx.x;
  int i = blockIdx.x * 256 + t;
  int p = 0, d = -1;
  if (i < n) {
    p = payIn[i];
    d = (int)((keyIn[i] >> 24) & 255u);
  }
  dig[t] = d;
  __syncthreads();
  if (i < n) {
    int local = 0;
    for (int j = 0; j < t; j++) local += (dig[j] == d) ? 1 : 0;
    int pos = base[d * NB + blockIdx.x] + local;
    if (pos < k) { perm[pos] = p; inv[p] = pos; oout[pos] = oin[p]; }
    else inv[p] = -1;
  }
}

// Fused gather + remap: blocks [0,k) gather rows, blocks [k, ...) remap edges.
// Bodies verbatim from the verified standalone kernels -> bit-identical.
__global__ __launch_bounds__(256) void gr_k(
    const float* __restrict__ H, const int* __restrict__ perm,
    const float* __restrict__ score, float* __restrict__ Ho,
    int* __restrict__ cs, int* __restrict__ cd, const int* __restrict__ inv,
    int k, int E) {
  int bidx = blockIdx.x;
  if (bidx < k) {
    int d = threadIdx.x;
    int p = perm[bidx];
    float s = score[p];
    if (d < 200)
      Ho[(size_t)bidx * 200 + d] = __fmul_rn(H[(size_t)p * 200 + d], s);
  } else {
    int e = (bidx - k) * 256 + threadIdx.x;
    if (e < E) {
      int a = cs[e];
      if (a >= 0) {
        int na = inv[a], nb = inv[cd[e]];
        bool valid = (na >= 0) && (nb >= 0);
        cs[e] = valid ? na : -1;
        cd[e] = valid ? nb : -1;
      }
    }
  }
}

// output: first cnt elements = h, rest zero (replaces memset + copy)
__global__ __launch_bounds__(256) void out_copy_k(const float* __restrict__ h,
                                                  float* __restrict__ out,
                                                  int cnt, int total) {
  int t = blockIdx.x * 256 + threadIdx.x;
  if (t < total) out[t] = (t < cnt) ? h[t] : 0.f;
}

// ---------------------------------------------------------------------------
extern "C" void kernel_launch(void* const* d_in, const int* in_sizes, int n_in,
                              void* d_out, int out_size, void* d_ws, size_t ws_size,
                              hipStream_t stream) {
  const int ID = 128, HD = 200;
  const int N = in_sizes[0] / ID;   // 50000
  const int E = in_sizes[1];        // 800000

  const float* x = (const float*)d_in[0];
  const int* src = (const int*)d_in[1];
  const int* dst = (const int*)d_in[2];
  const float* W[3]   = {(const float*)d_in[3], (const float*)d_in[7], (const float*)d_in[11]};
  const float* asv[3] = {(const float*)d_in[4], (const float*)d_in[8], (const float*)d_in[12]};
  const float* adv[3] = {(const float*)d_in[5], (const float*)d_in[9], (const float*)d_in[13]};
  const float* bv[3]  = {(const float*)d_in[6], (const float*)d_in[10], (const float*)d_in[14]};
  const float* Wrel  = (const float*)d_in[15];
  const float* Wroot = (const float*)d_in[16];
  const float* bpool = (const float*)d_in[17];

  char* ws = (char*)d_ws;
  float*    bufA  = (float*)(ws + 0);           // 40,000,000
  float*    bufB  = (float*)(ws + 40000000);    // 40,000,000
  float*    as_   = (float*)(ws + 80000000);    //   200,000
  float*    ad_   = (float*)(ws + 80200000);    //   200,000
  // ee_ region (3.4MB): GAT phase -> eeS; pooling phase -> radix scratch
  float*    den   = (float*)(ws + 84000000);    //   200,000
  float*    score = (float*)(ws + 84200000);    //   200,000
  int*      rank_ = (int*)(ws + 84400000);      //   200,000 (CSR count scratch)
  int*      perm_ = (int*)(ws + 84600000);      //   200,000
  int*      inv_  = (int*)(ws + 84800000);      //   200,000
  int*      origA = (int*)(ws + 85000000);      //   200,000
  int*      origB = (int*)(ws + 85200000);      //   200,000
  int*      rowptr= (int*)(ws + 85400000);      //   250,000 (N+1 ints)
  int*      curs  = (int*)(ws + 85650000);      //   200,000
  int*      csr   = (int*)(ws + 85850000);      // 3,200,000
  int*      csrc  = (int*)(ws + 89050000);      // 3,200,000
  int*      cdst  = (int*)(ws + 92250000);      // 3,200,000  -> total 95.45 MB

  int2* pk = (int2*)(ws + 89050000);     // GAT-phase reuse of csrc+cdst
  float* eeS = (float*)(ws + 80400000);  // GAT-phase reuse of ee_ region

  char* rx = ws + 80400000;              // pooling-phase radix scratch
  unsigned* keyA   = (unsigned*)(rx + 0 * 262144);
  unsigned* keyB   = (unsigned*)(rx + 1 * 262144);
  int*      payA   = (int*)(rx + 2 * 262144);
  int*      payB   = (int*)(rx + 3 * 262144);
  int*      rcounts= (int*)(rx + 4 * 262144);
  int*      rbase  = (int*)(rx + 5 * 262144);

  // Host-side fold_in(key(42), i) = threefry2x32(k=(0,42), x=(0,i)).
  uint32_t fk0[3], fk1[3];
  for (int i = 0; i < 3; i++) {
    uint32_t a = 0u, b = (uint32_t)i;
    threefry2x32(0u, 42u, a, b);
    fk0[i] = a; fk1[i] = b;
  }

  const int B256 = 256;
  // ---------------- CSR build (once) ----------------
  hipMemsetAsync(rank_, 0, (size_t)N * 4, stream);
  indeg_k<<<(E + 255) / 256, B256, 0, stream>>>(dst, rank_, E);
  scan_k<<<1, B256, 0, stream>>>(rank_, rowptr, curs, N);
  place_k<<<(E + 255) / 256, B256, 0, stream>>>(dst, curs, csr, E);
  sortrow_k<<<(N + 255) / 256, B256, 0, stream>>>(rowptr, csr, N);

  // ---------------- 3 GAT layers ----------------
  for (int i = 0; i < 3; i++) {
    const float* in = (i == 0) ? x : bufB;
    int K = (i == 0) ? ID : HD;
    gemm200_k<<<(N + 63) / 64, B256, 0, stream>>>(in, W[i], bufA, N, K);
    dual_dot_k<<<(N + 3) / 4, B256, 0, stream>>>(bufA, asv[i], adv[i], as_, ad_, N);
    eeden_k<<<(N + 255) / 256, B256, 0, stream>>>(rowptr, csr, src, as_, ad_,
                                                  pk, eeS, den, N);
    gat_out_k<<<(N + 3) / 4, B256, 0, stream>>>(rowptr, pk, eeS, den, bufA,
                                                bv[i], bufB, fk0[i], fk1[i], N);
  }

  // ---------------- SAGPooling loop ----------------
  einit_k<<<(E + 255) / 256, B256, 0, stream>>>(src, dst, csrc, cdst, origA, E, N);
  float* hcur = bufB;
  float* hnext = bufA;
  int* ocur = origA;
  int* onext = origB;
  int n = N;
  while (true) {
    int k = (n + 1) / 2;  // ceil(0.5 n)
    int NB = (n + 255) / 256;
    pool_agg_k<<<(n + 3) / 4, B256, 0, stream>>>(rowptr, csr, csrc, ocur, hcur,
                                                 Wrel, Wroot, bpool, score, n);
    rhenc_k<<<NB, B256, 0, stream>>>(score, keyA, payA, rcounts, n, NB);
    rscan_k<<<1, B256, 0, stream>>>(rcounts, rbase, NB);
    rscatter_k<<<NB, B256, 0, stream>>>(keyA, payA, rbase, keyB, payB, rcounts, n, NB, 0);
    rscan_k<<<1, B256, 0, stream>>>(rcounts, rbase, NB);
    rscatter_k<<<NB, B256, 0, stream>>>(keyB, payB, rbase, keyA, payA, rcounts, n, NB, 8);
    rscan_k<<<1, B256, 0, stream>>>(rcounts, rbase, NB);
    rscatter_k<<<NB, B256, 0, stream>>>(keyA, payA, rbase, keyB, payB, rcounts, n, NB, 16);
    rscan_k<<<1, B256, 0, stream>>>(rcounts, rbase, NB);
    rscatterF_k<<<NB, B256, 0, stream>>>(keyB, payB, rbase, ocur, onext, perm_, inv_,
                                         n, NB, k);
    gr_k<<<k + (E + 255) / 256, B256, 0, stream>>>(hcur, perm_, score, hnext,
                                                   csrc, cdst, inv_, k, E);
    { float* t = hcur; hcur = hnext; hnext = t; }
    { int* t = ocur; ocur = onext; onext = t; }
    n = k;
    if (n <= 512) break;
  }

  // ---------------- output: zeros(512,200) with first n rows = h -------------
  out_copy_k<<<(out_size + 255) / 256, B256, 0, stream>>>(hcur, (float*)d_out,
                                                          n * HD, out_size);
}